// Round 4
// baseline (183.969 us; speedup 1.0000x reference)
//
#include <hip/hip_runtime.h>

// HybridSymmetricLoss: B=65536, T=3, J=10 (fp32).
// C[tl][ta] = sum_jk BCE(assign[b,ta,jk], labels[b,tl,jk]);
// loss = min over 6 perms of mean C[t][perm[t]] + category BCE under argmin
// perm.  Logs in log2 space (clip -100/ln2), one ln2 scale at the end.
//
// Mapping: 4 lanes per b (quad).  Lane q owns jk4-chunks {q, q+4, ..., 20}
// plus chunk 24 on q==0 (25 chunks of 4 jk = 100).  All loads are float4
// with immediate offsets off one base per array (byte off = 400t + 16*jk4,
// base folded with 16q).  Reduction = 2 intra-quad shuffles (DPP, no LDS).
// e[tl][ta] = sum(l1[ta] + y[tl]*d[ta]);  BCE C = -ln2*e, so min C-sum ==
// max e-sum over perms.  16 b's per wave; epilogue on 16 lanes at once.
// Two-pass final sum via d_ws.

#define CLIP2 (-144.26950408889634f)   // -100 / ln(2)
#define LN2   (0.6931471805599453f)

__launch_bounds__(256)
__global__ void hybrid_pass1(const float* __restrict__ assign,
                             const float* __restrict__ cat,
                             const float* __restrict__ assign_lab,
                             const float* __restrict__ cat_lab,
                             float* __restrict__ ws, int B) {
    const int tid = blockIdx.x * blockDim.x + threadIdx.x;
    const int b   = tid >> 2;          // quad per batch element
    const int q   = threadIdx.x & 3;

    float lsum = 0.f;

    if (b < B) {
        const float* Abq = assign     + (size_t)b * 300 + 4 * q;
        const float* Ybq = assign_lab + (size_t)b * 300 + 4 * q;

        // category prefetch (12 B per b, quad-broadcast; only q==0 uses it)
        const float* cp = cat     + (size_t)b * 3;
        const float* gp = cat_lab + (size_t)b * 3;
        float cb0 = cp[0], cb1 = cp[1], cb2 = cp[2];
        float gb0 = gp[0], gb1 = gp[1], gb2 = gp[2];

        float dacc[3][3] = {{0.f,0.f,0.f},{0.f,0.f,0.f},{0.f,0.f,0.f}};
        float s1a[3]     = {0.f, 0.f, 0.f};

        // one jk4 chunk: 4 jk for all 3 t rows of both arrays
        auto do_chunk = [&](const float* Ap, const float* Yp) {
            float4 av[3], yv[3];
            #pragma unroll
            for (int t = 0; t < 3; ++t) {
                av[t] = *(const float4*)(Ap + t * 100);
                yv[t] = *(const float4*)(Yp + t * 100);
            }
            float d[3][4];
            #pragma unroll
            for (int t = 0; t < 3; ++t) {
                float a[4] = {av[t].x, av[t].y, av[t].z, av[t].w};
                #pragma unroll
                for (int c = 0; c < 4; ++c) {
                    float lp = fmaxf(__log2f(a[c]),        CLIP2);
                    float l1 = fmaxf(__log2f(1.0f - a[c]), CLIP2);
                    d[t][c] = lp - l1;
                    s1a[t] += l1;
                }
            }
            #pragma unroll
            for (int tl = 0; tl < 3; ++tl) {
                float y[4] = {yv[tl].x, yv[tl].y, yv[tl].z, yv[tl].w};
                #pragma unroll
                for (int ta = 0; ta < 3; ++ta) {
                    float acc = dacc[tl][ta];
                    #pragma unroll
                    for (int c = 0; c < 4; ++c)
                        acc = fmaf(y[c], d[ta][c], acc);
                    dacc[tl][ta] = acc;
                }
            }
        };

        #pragma unroll
        for (int k = 0; k < 6; ++k)
            do_chunk(Abq + 16 * k, Ybq + 16 * k);
        if (q == 0)                       // tail chunk jk4 = 24 (jk 96..99)
            do_chunk(Abq + 96, Ybq + 96);

        // fold s1 into the 9 partials, then 2-stage intra-quad butterfly
        float e[3][3];
        #pragma unroll
        for (int tl = 0; tl < 3; ++tl)
            #pragma unroll
            for (int ta = 0; ta < 3; ++ta)
                e[tl][ta] = dacc[tl][ta] + s1a[ta];

        #pragma unroll
        for (int off = 1; off <= 2; off <<= 1)
            #pragma unroll
            for (int tl = 0; tl < 3; ++tl)
                #pragma unroll
                for (int ta = 0; ta < 3; ++ta)
                    e[tl][ta] += __shfl_xor(e[tl][ta], off, 64);

        if (q == 0) {
            // min over perms of C = -ln2*e  ==  max over perms of e
            const int P0[6] = {0,0,1,1,2,2};
            const int P1[6] = {1,2,0,2,0,1};
            const int P2[6] = {2,1,2,0,1,0};
            float best = e[0][0] + e[1][1] + e[2][2];
            int bp0 = 0, bp1 = 1, bp2 = 2;
            #pragma unroll
            for (int p = 1; p < 6; ++p) {
                float l = e[0][P0[p]] + e[1][P1[p]] + e[2][P2[p]];
                if (l > best) { best = l; bp0 = P0[p]; bp1 = P1[p]; bp2 = P2[p]; }
            }

            float lp0 = fmaxf(__log2f(cb0), CLIP2), l10 = fmaxf(__log2f(1.f-cb0), CLIP2);
            float lp1 = fmaxf(__log2f(cb1), CLIP2), l11 = fmaxf(__log2f(1.f-cb1), CLIP2);
            float lp2 = fmaxf(__log2f(cb2), CLIP2), l12 = fmaxf(__log2f(1.f-cb2), CLIP2);

            float lpa = (bp0==0)?lp0:((bp0==1)?lp1:lp2);
            float l1a = (bp0==0)?l10:((bp0==1)?l11:l12);
            float lpb = (bp1==0)?lp0:((bp1==1)?lp1:lp2);
            float l1b = (bp1==0)?l10:((bp1==1)?l11:l12);
            float lpc = (bp2==0)?lp0:((bp2==1)?lp1:lp2);
            float l1c = (bp2==0)?l10:((bp2==1)?l11:l12);

            float csum = -(gb0*lpa + (1.f-gb0)*l1a
                         + gb1*lpb + (1.f-gb1)*l1b
                         + gb2*lpc + (1.f-gb2)*l1c);

            lsum = best * (-1.f/300.f) + csum * (1.f/3.f);
        }
    }

    // wave reduce (lsum nonzero only on q==0 lanes -> start at offset 4)
    #pragma unroll
    for (int off = 4; off <= 32; off <<= 1)
        lsum += __shfl_xor(lsum, off, 64);

    __shared__ float sred[4];
    if ((threadIdx.x & 63) == 0) sred[threadIdx.x >> 6] = lsum;
    __syncthreads();
    if (threadIdx.x == 0) {
        float s = (sred[0] + sred[1]) + (sred[2] + sred[3]);
        ws[blockIdx.x] = s * (LN2 / 65536.f);   // B = 65536 fixed
    }
}

__launch_bounds__(1024)
__global__ void hybrid_pass2(const float* __restrict__ ws,
                             float* __restrict__ out, int n) {
    float s = 0.f;
    for (int i = threadIdx.x; i < n; i += 1024) s += ws[i];
    #pragma unroll
    for (int off = 32; off > 0; off >>= 1) s += __shfl_xor(s, off, 64);
    __shared__ float sm[16];
    if ((threadIdx.x & 63) == 0) sm[threadIdx.x >> 6] = s;
    __syncthreads();
    if (threadIdx.x == 0) {
        float t = 0.f;
        #pragma unroll
        for (int i = 0; i < 16; ++i) t += sm[i];
        out[0] = t;
    }
}

extern "C" void kernel_launch(void* const* d_in, const int* in_sizes, int n_in,
                              void* d_out, int out_size, void* d_ws, size_t ws_size,
                              hipStream_t stream) {
    const float* assign     = (const float*)d_in[0];
    const float* cat        = (const float*)d_in[1];
    const float* assign_lab = (const float*)d_in[2];
    const float* cat_lab    = (const float*)d_in[3];
    float* out = (float*)d_out;
    float* ws  = (float*)d_ws;

    const int B = in_sizes[0] / 300;               // T*J*J = 300
    const int blocks = (B * 4 + 255) / 256;        // 4 lanes per b

    hybrid_pass1<<<blocks, 256, 0, stream>>>(assign, cat, assign_lab,
                                             cat_lab, ws, B);
    hybrid_pass2<<<1, 1024, 0, stream>>>(ws, out, blocks);
}